// Round 12
// baseline (158.366 us; speedup 1.0000x reference)
//
#include <hip/hip_runtime.h>
#include <hip/hip_bf16.h>

#define NB 8
#define PP 256
#define CC 128
#define XS 132     // padded row stride for f32 LDS tiles

typedef __bf16 bf16x8 __attribute__((ext_vector_type(8)));
typedef float float4v __attribute__((ext_vector_type(4)));

__device__ __forceinline__ float bf2f(unsigned short u) {
    union { unsigned int i; float f; } x; x.i = ((unsigned int)u) << 16; return x.f;
}
__device__ __forceinline__ unsigned short f2bf(float f) {
    union { float f; unsigned int i; } x; x.f = f;
    unsigned int r = x.i + 0x7fffu + ((x.i >> 16) & 1u);  // RNE
    return (unsigned short)(r >> 16);
}
__device__ __forceinline__ unsigned int pkbf2(float a, float b) {
    union { __hip_bfloat162 b2; unsigned int u; } cv;
    cv.b2 = __float22bfloat162_rn(make_float2(a, b));
    return cv.u;
}

// ONE prologue kernel, 197 blocks x 256 threads (float4 staging everywhere):
//  0..63   q: qwtb[n][j][b] = bf16( ((x@Wq)@W1)[b][j] )   (transposed)
//  64..127 k: kw = (x@Wk)@W1  (f32)
//  128..191 v: v = x@Wv       (f32)
//  192..195 W21f = (Wp2@W1) in bf16 MFMA-fragment order
//  196     bvec[j] = b1[j] + bp2@W1
__global__ __launch_bounds__(256) void stage1_kernel(
    const float* __restrict__ x, const float* __restrict__ Wq,
    const float* __restrict__ Wk, const float* __restrict__ Wv,
    const float* __restrict__ W1, const float* __restrict__ b1,
    const float* __restrict__ bp2, const float* __restrict__ Wp2,
    unsigned short* __restrict__ qwtb, float* __restrict__ kw,
    float* __restrict__ v, unsigned short* __restrict__ W21f,
    float* __restrict__ bvec)
{
    __shared__ __attribute__((aligned(16))) float Wbuf[CC * CC];    // 64 KB
    __shared__ __attribute__((aligned(16))) float xs[32 * XS];
    __shared__ __attribute__((aligned(16))) float tmp[32 * XS];
    const int t = threadIdx.x, bx = blockIdx.x;

    if (bx == 196) {
        if (t < 128) {
            float s = b1[t];
#pragma unroll 8
            for (int c = 0; c < CC; ++c) s = fmaf(bp2[c], W1[c * CC + t], s);
            bvec[t] = s;
        }
        return;
    }

    const int tc = t & 31, tr = t >> 5;
    const int j0 = tc * 4, r0 = tr * 4;

    if (bx < 192) {
        const int kind = bx >> 6;            // 0=q, 1=k, 2=v
        const int row0 = (bx & 63) * 32;
        const float* Wsrc = (kind == 0) ? Wq : (kind == 1) ? Wk : Wv;
#pragma unroll 4
        for (int i = 0; i < 16; ++i)
            ((float4*)Wbuf)[i * 256 + t] = ((const float4*)Wsrc)[i * 256 + t];
#pragma unroll
        for (int i = 0; i < 4; ++i) {
            int idx = i * 256 + t; int r = idx >> 5, c4 = idx & 31;
            *(float4*)&xs[r * XS + c4 * 4] =
                ((const float4*)(x + (size_t)(row0 + r) * CC))[c4];
        }
        __syncthreads();
        float acc[4][4];
#pragma unroll
        for (int i = 0; i < 4; ++i)
#pragma unroll
            for (int jj = 0; jj < 4; ++jj) acc[i][jj] = 0.f;
#pragma unroll 2
        for (int c = 0; c < CC; ++c) {
            float4 w4 = *(const float4*)&Wbuf[c * CC + j0];
#pragma unroll
            for (int i = 0; i < 4; ++i) {
                float xv = xs[(r0 + i) * XS + c];
                acc[i][0] = fmaf(xv, w4.x, acc[i][0]); acc[i][1] = fmaf(xv, w4.y, acc[i][1]);
                acc[i][2] = fmaf(xv, w4.z, acc[i][2]); acc[i][3] = fmaf(xv, w4.w, acc[i][3]);
            }
        }
        if (kind == 2) {
#pragma unroll
            for (int i = 0; i < 4; ++i)
                *(float4*)&v[(size_t)(row0 + r0 + i) * CC + j0] =
                    make_float4(acc[i][0], acc[i][1], acc[i][2], acc[i][3]);
            return;
        }
        // write tmp, restage Wbuf with W1, second GEMM
#pragma unroll
        for (int i = 0; i < 4; ++i)
            *(float4*)&tmp[(r0 + i) * XS + j0] =
                make_float4(acc[i][0], acc[i][1], acc[i][2], acc[i][3]);
        __syncthreads();
#pragma unroll 4
        for (int i = 0; i < 16; ++i)
            ((float4*)Wbuf)[i * 256 + t] = ((const float4*)W1)[i * 256 + t];
        __syncthreads();
        float acc2[4][4];
#pragma unroll
        for (int i = 0; i < 4; ++i)
#pragma unroll
            for (int jj = 0; jj < 4; ++jj) acc2[i][jj] = 0.f;
#pragma unroll 2
        for (int c = 0; c < CC; ++c) {
            float4 w4 = *(const float4*)&Wbuf[c * CC + j0];
#pragma unroll
            for (int i = 0; i < 4; ++i) {
                float xv = tmp[(r0 + i) * XS + c];
                acc2[i][0] = fmaf(xv, w4.x, acc2[i][0]); acc2[i][1] = fmaf(xv, w4.y, acc2[i][1]);
                acc2[i][2] = fmaf(xv, w4.z, acc2[i][2]); acc2[i][3] = fmaf(xv, w4.w, acc2[i][3]);
            }
        }
        if (kind == 0) {
            int n = row0 >> 8, b0 = row0 & 255;
#pragma unroll
            for (int jj = 0; jj < 4; ++jj) {
                ushort4 pk;
                pk.x = f2bf(acc2[0][jj]); pk.y = f2bf(acc2[1][jj]);
                pk.z = f2bf(acc2[2][jj]); pk.w = f2bf(acc2[3][jj]);
                *(ushort4*)(qwtb + (size_t)(n * CC + j0 + jj) * PP + b0 + r0) = pk;
            }
        } else {
#pragma unroll
            for (int i = 0; i < 4; ++i)
                *(float4*)&kw[(size_t)(row0 + r0 + i) * CC + j0] =
                    make_float4(acc2[i][0], acc2[i][1], acc2[i][2], acc2[i][3]);
        }
    } else {
        // W21f: rows of Wp2 @ W1, stored bf16 fragment order
        const int row0 = (bx - 192) * 32;
#pragma unroll 4
        for (int i = 0; i < 16; ++i)
            ((float4*)Wbuf)[i * 256 + t] = ((const float4*)W1)[i * 256 + t];
#pragma unroll
        for (int i = 0; i < 4; ++i) {
            int idx = i * 256 + t; int r = idx >> 5, c4 = idx & 31;
            *(float4*)&xs[r * XS + c4 * 4] =
                ((const float4*)(Wp2 + (size_t)(row0 + r) * CC))[c4];
        }
        __syncthreads();
        float acc[4][4];
#pragma unroll
        for (int i = 0; i < 4; ++i)
#pragma unroll
            for (int jj = 0; jj < 4; ++jj) acc[i][jj] = 0.f;
#pragma unroll 2
        for (int c = 0; c < CC; ++c) {
            float4 w4 = *(const float4*)&Wbuf[c * CC + j0];
#pragma unroll
            for (int i = 0; i < 4; ++i) {
                float xv = xs[(r0 + i) * XS + c];
                acc[i][0] = fmaf(xv, w4.x, acc[i][0]); acc[i][1] = fmaf(xv, w4.y, acc[i][1]);
                acc[i][2] = fmaf(xv, w4.z, acc[i][2]); acc[i][3] = fmaf(xv, w4.w, acc[i][3]);
            }
        }
#pragma unroll
        for (int i = 0; i < 4; ++i)
#pragma unroll
            for (int jj = 0; jj < 4; ++jj) {
                int k = row0 + r0 + i, j = j0 + jj;
                int kk = k >> 5, qd = (k >> 3) & 3, e = k & 7;
                int jt = j >> 4, ln = j & 15, lane = qd * 16 + ln;
                W21f[(((kk * 8 + jt) * 64) + lane) * 8 + e] = f2bf(acc[i][jj]);
            }
    }
}

// One block per (n,a). 2 chunks x 2 m-tiles: each B fragment read feeds 2 MFMAs
// (halves LDS traffic vs 4x1). A built from LDS broadcast reads + HW packed cvt.
// B in fragment-order LDS (zero conflicts). float4 AV epilogue.
__global__ __launch_bounds__(256, 3) void attn_kernel(
    const float* __restrict__ x, const float* __restrict__ pos,
    const float* __restrict__ Wp1, const float* __restrict__ bp1,
    const float* __restrict__ W2, const float* __restrict__ b2,
    const unsigned short* __restrict__ W21f, const float* __restrict__ bvec,
    const unsigned short* __restrict__ qwtb, const float* __restrict__ kw,
    const float* __restrict__ v, float* __restrict__ out)
{
    __shared__ __attribute__((aligned(16))) unsigned short Bs[128 * 128]; // frag order
    __shared__ float p0s[PP], p1s[PP];
    __shared__ float wa[CC], wb[CC], bpv[CC];
    __shared__ float logits[PP];
    __shared__ float red[8];
    __shared__ float avp[8 * 128];

    const int t = threadIdx.x;
    const int n = blockIdx.x >> 8, a = blockIdx.x & 255;
    const int lane = t & 63, wv = t >> 6;
    const int ln = lane & 15, quad = lane >> 4;

    if (t < CC) {
        wa[t]  = Wp1[t];
        wb[t]  = Wp1[CC + t];
        bpv[t] = bp1[t];
    }
    {
        const float2* pr = (const float2*)(pos + (size_t)(n * PP + a) * PP * 2);
        float2 pp = pr[t];
        p0s[t] = pp.x;
        p1s[t] = pp.y;
    }
    {   // stage Bs: straight 16B copies (global coalesced, LDS conflict-free)
        const uint4* src = (const uint4*)W21f;
        uint4* dst = (uint4*)Bs;
#pragma unroll
        for (int i = 0; i < 8; ++i) dst[i * 256 + t] = src[i * 256 + t];
    }
    const float b2f = b2[0];

    // per-lane epilogue constants (col j = nt*16 + ln)
    float w2v[8], kbv[8];
    {
        const float* kwrow = kw + (size_t)(n * PP + a) * CC;
#pragma unroll
        for (int nt = 0; nt < 8; ++nt) {
            int j = nt * 16 + ln;
            w2v[nt] = W2[j];
            kbv[nt] = bvec[j] - kwrow[j];
        }
    }
    __syncthreads();

#pragma unroll 1
    for (int chunk = 0; chunk < 2; ++chunk) {
        const int rbase = chunk * 128 + wv * 32;
        float P0[2], P1[2];
#pragma unroll
        for (int i = 0; i < 2; ++i) {
            P0[i] = p0s[rbase + i * 16 + ln];
            P1[i] = p1s[rbase + i * 16 + ln];
        }

        // prefetch qw epilogue values (bf16 transposed [n][j][b]) — drains behind MFMA
        ushort4 qv4[2][8];
#pragma unroll
        for (int i = 0; i < 2; ++i)
#pragma unroll
            for (int nt = 0; nt < 8; ++nt)
                qv4[i][nt] = *(const ushort4*)(qwtb + (size_t)(n * CC + nt * 16 + ln) * PP
                                               + rbase + i * 16 + quad * 4);

        float4v acc[2][8];
#pragma unroll
        for (int i = 0; i < 2; ++i)
#pragma unroll
            for (int j = 0; j < 8; ++j) acc[i][j] = (float4v)0.f;

#pragma unroll 1
        for (int kk = 0; kk < 4; ++kk) {
            const int ko = kk * 32 + quad * 8;
            // broadcast LDS reads (quad-uniform), shared by both m-tiles
            float4 a0 = *(const float4*)&wa[ko],  a1 = *(const float4*)&wa[ko + 4];
            float4 c0 = *(const float4*)&wb[ko],  c1 = *(const float4*)&wb[ko + 4];
            float4 d0 = *(const float4*)&bpv[ko], d1 = *(const float4*)&bpv[ko + 4];
            bf16x8 af0, af1;
            {
                float h0 = fmaxf(fmaf(P0[0], a0.x, fmaf(P1[0], c0.x, d0.x)), 0.f);
                float h1 = fmaxf(fmaf(P0[0], a0.y, fmaf(P1[0], c0.y, d0.y)), 0.f);
                float h2 = fmaxf(fmaf(P0[0], a0.z, fmaf(P1[0], c0.z, d0.z)), 0.f);
                float h3 = fmaxf(fmaf(P0[0], a0.w, fmaf(P1[0], c0.w, d0.w)), 0.f);
                float h4 = fmaxf(fmaf(P0[0], a1.x, fmaf(P1[0], c1.x, d1.x)), 0.f);
                float h5 = fmaxf(fmaf(P0[0], a1.y, fmaf(P1[0], c1.y, d1.y)), 0.f);
                float h6 = fmaxf(fmaf(P0[0], a1.z, fmaf(P1[0], c1.z, d1.z)), 0.f);
                float h7 = fmaxf(fmaf(P0[0], a1.w, fmaf(P1[0], c1.w, d1.w)), 0.f);
                union { bf16x8 v8; unsigned int u[4]; } cv;
                cv.u[0] = pkbf2(h0, h1); cv.u[1] = pkbf2(h2, h3);
                cv.u[2] = pkbf2(h4, h5); cv.u[3] = pkbf2(h6, h7);
                af0 = cv.v8;
            }
            {
                float h0 = fmaxf(fmaf(P0[1], a0.x, fmaf(P1[1], c0.x, d0.x)), 0.f);
                float h1 = fmaxf(fmaf(P0[1], a0.y, fmaf(P1[1], c0.y, d0.y)), 0.f);
                float h2 = fmaxf(fmaf(P0[1], a0.z, fmaf(P1[1], c0.z, d0.z)), 0.f);
                float h3 = fmaxf(fmaf(P0[1], a0.w, fmaf(P1[1], c0.w, d0.w)), 0.f);
                float h4 = fmaxf(fmaf(P0[1], a1.x, fmaf(P1[1], c1.x, d1.x)), 0.f);
                float h5 = fmaxf(fmaf(P0[1], a1.y, fmaf(P1[1], c1.y, d1.y)), 0.f);
                float h6 = fmaxf(fmaf(P0[1], a1.z, fmaf(P1[1], c1.z, d1.z)), 0.f);
                float h7 = fmaxf(fmaf(P0[1], a1.w, fmaf(P1[1], c1.w, d1.w)), 0.f);
                union { bf16x8 v8; unsigned int u[4]; } cv;
                cv.u[0] = pkbf2(h0, h1); cv.u[1] = pkbf2(h2, h3);
                cv.u[2] = pkbf2(h4, h5); cv.u[3] = pkbf2(h6, h7);
                af1 = cv.v8;
            }
#pragma unroll
            for (int j = 0; j < 8; ++j) {
                bf16x8 bfr = *(const bf16x8*)(Bs + (((kk * 8 + j) * 64) + lane) * 8);
                acc[0][j] = __builtin_amdgcn_mfma_f32_16x16x32_bf16(af0, bfr, acc[0][j], 0, 0, 0);
                acc[1][j] = __builtin_amdgcn_mfma_f32_16x16x32_bf16(af1, bfr, acc[1][j], 0, 0, 0);
            }
        }

        // epilogue: D row = i*16 + quad*4 + r, col = nt*16 + ln
#pragma unroll
        for (int i = 0; i < 2; ++i) {
            float s0 = 0.f, s1 = 0.f, s2 = 0.f, s3 = 0.f;
#pragma unroll
            for (int nt = 0; nt < 8; ++nt) {
                float kb = kbv[nt], w2 = w2v[nt];
                s0 = fmaf(fmaxf(acc[i][nt][0] + bf2f(qv4[i][nt].x) + kb, 0.f), w2, s0);
                s1 = fmaf(fmaxf(acc[i][nt][1] + bf2f(qv4[i][nt].y) + kb, 0.f), w2, s1);
                s2 = fmaf(fmaxf(acc[i][nt][2] + bf2f(qv4[i][nt].z) + kb, 0.f), w2, s2);
                s3 = fmaf(fmaxf(acc[i][nt][3] + bf2f(qv4[i][nt].w) + kb, 0.f), w2, s3);
            }
            float sr[4] = {s0, s1, s2, s3};
#pragma unroll
            for (int r = 0; r < 4; ++r) {
                float s = sr[r];
                s += __shfl_xor(s, 1);
                s += __shfl_xor(s, 2);
                s += __shfl_xor(s, 4);
                s += __shfl_xor(s, 8);
                if (ln == 0) logits[rbase + i * 16 + quad * 4 + r] = s + b2f;
            }
        }
    }
    __syncthreads();   // logits ready

    // ---- softmax over 256 logits: wave shfl reductions ----
    float lv = logits[t];
    float wm = lv;
#pragma unroll
    for (int d = 1; d < 64; d <<= 1) wm = fmaxf(wm, __shfl_xor(wm, d));
    if (lane == 0) red[wv] = wm;
    __syncthreads();
    float m = fmaxf(fmaxf(red[0], red[1]), fmaxf(red[2], red[3]));
    float e = __expf(lv - m);
    float es = e;
#pragma unroll
    for (int d = 1; d < 64; d <<= 1) es += __shfl_xor(es, d);
    if (lane == 0) red[4 + wv] = es;
    __syncthreads();
    float denom = red[4] + red[5] + red[6] + red[7];
    logits[t] = e / denom;
    __syncthreads();

    // ---- out[n,a,c] = x[n,a,c] + sum_b att[b] * v[n,b,c], float4 over c ----
    {
        int c4 = (t & 31) * 4, bg = t >> 5;          // 8 b-groups of 32
        const float* vp = v + (size_t)(n * PP + bg * 32) * CC + c4;
        float4 av = make_float4(0.f, 0.f, 0.f, 0.f);
#pragma unroll 4
        for (int b = 0; b < 32; ++b) {
            float w = logits[bg * 32 + b];
            float4 vv = *(const float4*)(vp + (size_t)b * CC);
            av.x = fmaf(w, vv.x, av.x); av.y = fmaf(w, vv.y, av.y);
            av.z = fmaf(w, vv.z, av.z); av.w = fmaf(w, vv.w, av.w);
        }
        *(float4*)&avp[bg * 128 + c4] = av;
    }
    __syncthreads();
    if (t < 128) {
        int oidx = (n * PP + a) * CC + t;
        float s = x[oidx];
#pragma unroll
        for (int g = 0; g < 8; ++g) s += avp[g * 128 + t];
        out[oidx] = s;
    }
}

extern "C" void kernel_launch(void* const* d_in, const int* in_sizes, int n_in,
                              void* d_out, int out_size, void* d_ws, size_t ws_size,
                              hipStream_t stream) {
    const float* x   = (const float*)d_in[0];
    const float* pos = (const float*)d_in[1];
    const float* Wq  = (const float*)d_in[2];
    const float* Wk  = (const float*)d_in[3];
    const float* Wv  = (const float*)d_in[4];
    const float* W1  = (const float*)d_in[5];
    const float* b1  = (const float*)d_in[6];
    const float* W2  = (const float*)d_in[7];
    const float* b2  = (const float*)d_in[8];
    const float* Wp1 = (const float*)d_in[9];
    const float* bp1 = (const float*)d_in[10];
    const float* Wp2 = (const float*)d_in[11];
    const float* bp2 = (const float*)d_in[12];
    float* out = (float*)d_out;

    float* ws   = (float*)d_ws;
    float* bvec = ws;                  // 128 f32
    float* kw   = bvec + 128;          // 262144 f32
    float* v    = kw + 262144;         // 262144 f32
    unsigned short* qwtb = (unsigned short*)(v + 262144);  // 262144 bf16
    unsigned short* W21f = qwtb + 262144;                  // 16384 bf16 (frag order)

    stage1_kernel<<<197, 256, 0, stream>>>(x, Wq, Wk, Wv, W1, b1, bp2, Wp2,
                                           qwtb, kw, v, W21f, bvec);
    attn_kernel<<<NB * PP, 256, 0, stream>>>(x, pos, Wp1, bp1, W2, b2,
                                             W21f, bvec, qwtb, kw, v, out);
}

// Round 13
// 142.172 us; speedup vs baseline: 1.1139x; 1.1139x over previous
//
#include <hip/hip_runtime.h>
#include <hip/hip_bf16.h>

#define NB 8
#define PP 256
#define CC 128
#define XS 132     // padded row stride for f32 LDS tiles

typedef __bf16 bf16x8 __attribute__((ext_vector_type(8)));
typedef float float4v __attribute__((ext_vector_type(4)));

__device__ __forceinline__ float bf2f(unsigned short u) {
    union { unsigned int i; float f; } x; x.i = ((unsigned int)u) << 16; return x.f;
}
__device__ __forceinline__ unsigned short f2bf(float f) {
    union { float f; unsigned int i; } x; x.f = f;
    unsigned int r = x.i + 0x7fffu + ((x.i >> 16) & 1u);  // RNE
    return (unsigned short)(r >> 16);
}
__device__ __forceinline__ unsigned int pk2(float a, float b) {
    return (unsigned int)f2bf(a) | ((unsigned int)f2bf(b) << 16);
}

// ONE prologue kernel, 197 blocks x 256 threads.
// GEMM inner loops c-blocked by 4 with float4 LDS reads (2 ds_read_b128 per c
// vs 5 LDS instrs per c in R11 — stage1 was LDS-issue-bound at 4 waves/CU).
//  0..63   q: qwtb[n][j][b] = bf16( ((x@Wq)@W1)[b][j] )   (transposed)
//  64..127 k: kw = (x@Wk)@W1  (f32)
//  128..191 v: v = x@Wv       (f32)
//  192..195 W21f = (Wp2@W1) in bf16 MFMA-fragment order
//  196     bvec[j] = b1[j] + bp2@W1
__global__ __launch_bounds__(256) void stage1_kernel(
    const float* __restrict__ x, const float* __restrict__ Wq,
    const float* __restrict__ Wk, const float* __restrict__ Wv,
    const float* __restrict__ W1, const float* __restrict__ b1,
    const float* __restrict__ bp2, const float* __restrict__ Wp2,
    unsigned short* __restrict__ qwtb, float* __restrict__ kw,
    float* __restrict__ v, unsigned short* __restrict__ W21f,
    float* __restrict__ bvec)
{
    __shared__ __attribute__((aligned(16))) float Wbuf[CC * CC];    // 64 KB
    __shared__ __attribute__((aligned(16))) float xs[32 * XS];
    __shared__ __attribute__((aligned(16))) float tmp[32 * XS];
    const int t = threadIdx.x, bx = blockIdx.x;

    if (bx == 196) {
        if (t < 128) {
            float s = b1[t];
#pragma unroll 8
            for (int c = 0; c < CC; ++c) s = fmaf(bp2[c], W1[c * CC + t], s);
            bvec[t] = s;
        }
        return;
    }

    const int tc = t & 31, tr = t >> 5;
    const int j0 = tc * 4, r0 = tr * 4;

    if (bx < 192) {
        const int kind = bx >> 6;            // 0=q, 1=k, 2=v
        const int row0 = (bx & 63) * 32;
        const float* Wsrc = (kind == 0) ? Wq : (kind == 1) ? Wk : Wv;
#pragma unroll 4
        for (int i = 0; i < 16; ++i)
            ((float4*)Wbuf)[i * 256 + t] = ((const float4*)Wsrc)[i * 256 + t];
#pragma unroll
        for (int i = 0; i < 4; ++i) {
            int idx = i * 256 + t; int r = idx >> 5, c4 = idx & 31;
            *(float4*)&xs[r * XS + c4 * 4] =
                ((const float4*)(x + (size_t)(row0 + r) * CC))[c4];
        }
        __syncthreads();
        float4 acc[4];
#pragma unroll
        for (int i = 0; i < 4; ++i) acc[i] = make_float4(0.f, 0.f, 0.f, 0.f);
#pragma unroll 2
        for (int c4 = 0; c4 < 32; ++c4) {
            float4 xv0 = *(const float4*)&xs[(r0 + 0) * XS + c4 * 4];
            float4 xv1 = *(const float4*)&xs[(r0 + 1) * XS + c4 * 4];
            float4 xv2 = *(const float4*)&xs[(r0 + 2) * XS + c4 * 4];
            float4 xv3 = *(const float4*)&xs[(r0 + 3) * XS + c4 * 4];
            const float xr[4][4] = {{xv0.x, xv0.y, xv0.z, xv0.w},
                                    {xv1.x, xv1.y, xv1.z, xv1.w},
                                    {xv2.x, xv2.y, xv2.z, xv2.w},
                                    {xv3.x, xv3.y, xv3.z, xv3.w}};
#pragma unroll
            for (int cc = 0; cc < 4; ++cc) {
                float4 w4 = *(const float4*)&Wbuf[(c4 * 4 + cc) * CC + j0];
#pragma unroll
                for (int i = 0; i < 4; ++i) {
                    acc[i].x = fmaf(xr[i][cc], w4.x, acc[i].x);
                    acc[i].y = fmaf(xr[i][cc], w4.y, acc[i].y);
                    acc[i].z = fmaf(xr[i][cc], w4.z, acc[i].z);
                    acc[i].w = fmaf(xr[i][cc], w4.w, acc[i].w);
                }
            }
        }
        if (kind == 2) {
#pragma unroll
            for (int i = 0; i < 4; ++i)
                *(float4*)&v[(size_t)(row0 + r0 + i) * CC + j0] = acc[i];
            return;
        }
        // write tmp, restage Wbuf with W1, second GEMM
#pragma unroll
        for (int i = 0; i < 4; ++i)
            *(float4*)&tmp[(r0 + i) * XS + j0] = acc[i];
        __syncthreads();
#pragma unroll 4
        for (int i = 0; i < 16; ++i)
            ((float4*)Wbuf)[i * 256 + t] = ((const float4*)W1)[i * 256 + t];
        __syncthreads();
        float4 acc2[4];
#pragma unroll
        for (int i = 0; i < 4; ++i) acc2[i] = make_float4(0.f, 0.f, 0.f, 0.f);
#pragma unroll 2
        for (int c4 = 0; c4 < 32; ++c4) {
            float4 xv0 = *(const float4*)&tmp[(r0 + 0) * XS + c4 * 4];
            float4 xv1 = *(const float4*)&tmp[(r0 + 1) * XS + c4 * 4];
            float4 xv2 = *(const float4*)&tmp[(r0 + 2) * XS + c4 * 4];
            float4 xv3 = *(const float4*)&tmp[(r0 + 3) * XS + c4 * 4];
            const float xr[4][4] = {{xv0.x, xv0.y, xv0.z, xv0.w},
                                    {xv1.x, xv1.y, xv1.z, xv1.w},
                                    {xv2.x, xv2.y, xv2.z, xv2.w},
                                    {xv3.x, xv3.y, xv3.z, xv3.w}};
#pragma unroll
            for (int cc = 0; cc < 4; ++cc) {
                float4 w4 = *(const float4*)&Wbuf[(c4 * 4 + cc) * CC + j0];
#pragma unroll
                for (int i = 0; i < 4; ++i) {
                    acc2[i].x = fmaf(xr[i][cc], w4.x, acc2[i].x);
                    acc2[i].y = fmaf(xr[i][cc], w4.y, acc2[i].y);
                    acc2[i].z = fmaf(xr[i][cc], w4.z, acc2[i].z);
                    acc2[i].w = fmaf(xr[i][cc], w4.w, acc2[i].w);
                }
            }
        }
        if (kind == 0) {
            int n = row0 >> 8, b0 = row0 & 255;
            const float a2[4][4] = {{acc2[0].x, acc2[0].y, acc2[0].z, acc2[0].w},
                                    {acc2[1].x, acc2[1].y, acc2[1].z, acc2[1].w},
                                    {acc2[2].x, acc2[2].y, acc2[2].z, acc2[2].w},
                                    {acc2[3].x, acc2[3].y, acc2[3].z, acc2[3].w}};
#pragma unroll
            for (int jj = 0; jj < 4; ++jj) {
                ushort4 pk;
                pk.x = f2bf(a2[0][jj]); pk.y = f2bf(a2[1][jj]);
                pk.z = f2bf(a2[2][jj]); pk.w = f2bf(a2[3][jj]);
                *(ushort4*)(qwtb + (size_t)(n * CC + j0 + jj) * PP + b0 + r0) = pk;
            }
        } else {
#pragma unroll
            for (int i = 0; i < 4; ++i)
                *(float4*)&kw[(size_t)(row0 + r0 + i) * CC + j0] = acc2[i];
        }
    } else {
        // W21f: rows of Wp2 @ W1, stored bf16 fragment order
        const int row0 = (bx - 192) * 32;
#pragma unroll 4
        for (int i = 0; i < 16; ++i)
            ((float4*)Wbuf)[i * 256 + t] = ((const float4*)W1)[i * 256 + t];
#pragma unroll
        for (int i = 0; i < 4; ++i) {
            int idx = i * 256 + t; int r = idx >> 5, c4 = idx & 31;
            *(float4*)&xs[r * XS + c4 * 4] =
                ((const float4*)(Wp2 + (size_t)(row0 + r) * CC))[c4];
        }
        __syncthreads();
        float4 acc[4];
#pragma unroll
        for (int i = 0; i < 4; ++i) acc[i] = make_float4(0.f, 0.f, 0.f, 0.f);
#pragma unroll 2
        for (int c4 = 0; c4 < 32; ++c4) {
            float4 xv0 = *(const float4*)&xs[(r0 + 0) * XS + c4 * 4];
            float4 xv1 = *(const float4*)&xs[(r0 + 1) * XS + c4 * 4];
            float4 xv2 = *(const float4*)&xs[(r0 + 2) * XS + c4 * 4];
            float4 xv3 = *(const float4*)&xs[(r0 + 3) * XS + c4 * 4];
            const float xr[4][4] = {{xv0.x, xv0.y, xv0.z, xv0.w},
                                    {xv1.x, xv1.y, xv1.z, xv1.w},
                                    {xv2.x, xv2.y, xv2.z, xv2.w},
                                    {xv3.x, xv3.y, xv3.z, xv3.w}};
#pragma unroll
            for (int cc = 0; cc < 4; ++cc) {
                float4 w4 = *(const float4*)&Wbuf[(c4 * 4 + cc) * CC + j0];
#pragma unroll
                for (int i = 0; i < 4; ++i) {
                    acc[i].x = fmaf(xr[i][cc], w4.x, acc[i].x);
                    acc[i].y = fmaf(xr[i][cc], w4.y, acc[i].y);
                    acc[i].z = fmaf(xr[i][cc], w4.z, acc[i].z);
                    acc[i].w = fmaf(xr[i][cc], w4.w, acc[i].w);
                }
            }
        }
        const float a4[4][4] = {{acc[0].x, acc[0].y, acc[0].z, acc[0].w},
                                {acc[1].x, acc[1].y, acc[1].z, acc[1].w},
                                {acc[2].x, acc[2].y, acc[2].z, acc[2].w},
                                {acc[3].x, acc[3].y, acc[3].z, acc[3].w}};
#pragma unroll
        for (int i = 0; i < 4; ++i)
#pragma unroll
            for (int jj = 0; jj < 4; ++jj) {
                int k = row0 + r0 + i, j = j0 + jj;
                int kk = k >> 5, qd = (k >> 3) & 3, e = k & 7;
                int jt = j >> 4, ln = j & 15, lane = qd * 16 + ln;
                W21f[(((kk * 8 + jt) * 64) + lane) * 8 + e] = f2bf(a4[i][jj]);
            }
    }
}

// One block per (n,a). R11-proven structure VERBATIM: 4 chunks x 1 m-tile,
// A built per-kk from LDS broadcast float4 reads, bf16 pk2 pack, bf16 MFMA;
// B in fragment-order LDS (zero conflicts); float4 AV epilogue.
__global__ __launch_bounds__(256, 3) void attn_kernel(
    const float* __restrict__ x, const float* __restrict__ pos,
    const float* __restrict__ Wp1, const float* __restrict__ bp1,
    const float* __restrict__ W2, const float* __restrict__ b2,
    const unsigned short* __restrict__ W21f, const float* __restrict__ bvec,
    const unsigned short* __restrict__ qwtb, const float* __restrict__ kw,
    const float* __restrict__ v, float* __restrict__ out)
{
    __shared__ __attribute__((aligned(16))) unsigned short Bs[128 * 128]; // frag order
    __shared__ float p0s[PP], p1s[PP];
    __shared__ float wa[CC], wb[CC], bpv[CC];
    __shared__ float logits[PP];
    __shared__ float red[8];
    __shared__ float avp[8 * 128];

    const int t = threadIdx.x;
    const int n = blockIdx.x >> 8, a = blockIdx.x & 255;
    const int lane = t & 63, wv = t >> 6;
    const int ln = lane & 15, quad = lane >> 4;

    if (t < CC) {
        wa[t]  = Wp1[t];
        wb[t]  = Wp1[CC + t];
        bpv[t] = bp1[t];
    }
    {
        const float2* pr = (const float2*)(pos + (size_t)(n * PP + a) * PP * 2);
        float2 pp = pr[t];
        p0s[t] = pp.x;
        p1s[t] = pp.y;
    }
    {   // stage Bs: straight 16B copies (global coalesced, LDS conflict-free)
        const uint4* src = (const uint4*)W21f;
        uint4* dst = (uint4*)Bs;
#pragma unroll
        for (int i = 0; i < 8; ++i) dst[i * 256 + t] = src[i * 256 + t];
    }
    const float b2f = b2[0];

    // per-lane epilogue constants (col j = nt*16 + ln)
    float w2v[8], kbv[8];
    {
        const float* kwrow = kw + (size_t)(n * PP + a) * CC;
#pragma unroll
        for (int nt = 0; nt < 8; ++nt) {
            int j = nt * 16 + ln;
            w2v[nt] = W2[j];
            kbv[nt] = bvec[j] - kwrow[j];
        }
    }
    __syncthreads();

#pragma unroll 1
    for (int chunk = 0; chunk < 4; ++chunk) {
        const int rbase = chunk * 64 + wv * 16;
        const float P0 = p0s[rbase + ln];
        const float P1 = p1s[rbase + ln];

        // prefetch qw epilogue values (bf16 transposed [n][j][b]) — drains behind MFMA
        ushort4 qv4[8];
#pragma unroll
        for (int nt = 0; nt < 8; ++nt)
            qv4[nt] = *(const ushort4*)(qwtb + (size_t)(n * CC + nt * 16 + ln) * PP
                                        + rbase + quad * 4);

        float4v acc[8];
#pragma unroll
        for (int j = 0; j < 8; ++j) acc[j] = (float4v)0.f;

#pragma unroll 1
        for (int kk = 0; kk < 4; ++kk) {
            const int ko = kk * 32 + quad * 8;
            // A-fragment in registers from LDS broadcast reads: A[m=ln][k=ko+e]
            float4 a0 = *(const float4*)&wa[ko],  a1 = *(const float4*)&wa[ko + 4];
            float4 c0 = *(const float4*)&wb[ko],  c1 = *(const float4*)&wb[ko + 4];
            float4 d0 = *(const float4*)&bpv[ko], d1 = *(const float4*)&bpv[ko + 4];
            float h0 = fmaxf(fmaf(P0, a0.x, fmaf(P1, c0.x, d0.x)), 0.f);
            float h1 = fmaxf(fmaf(P0, a0.y, fmaf(P1, c0.y, d0.y)), 0.f);
            float h2 = fmaxf(fmaf(P0, a0.z, fmaf(P1, c0.z, d0.z)), 0.f);
            float h3 = fmaxf(fmaf(P0, a0.w, fmaf(P1, c0.w, d0.w)), 0.f);
            float h4 = fmaxf(fmaf(P0, a1.x, fmaf(P1, c1.x, d1.x)), 0.f);
            float h5 = fmaxf(fmaf(P0, a1.y, fmaf(P1, c1.y, d1.y)), 0.f);
            float h6 = fmaxf(fmaf(P0, a1.z, fmaf(P1, c1.z, d1.z)), 0.f);
            float h7 = fmaxf(fmaf(P0, a1.w, fmaf(P1, c1.w, d1.w)), 0.f);
            union { bf16x8 v8; unsigned int u[4]; } cv;
            cv.u[0] = pk2(h0, h1); cv.u[1] = pk2(h2, h3);
            cv.u[2] = pk2(h4, h5); cv.u[3] = pk2(h6, h7);
            bf16x8 af = cv.v8;
#pragma unroll
            for (int j = 0; j < 8; ++j) {
                bf16x8 bfr = *(const bf16x8*)(Bs + (((kk * 8 + j) * 64) + lane) * 8);
                acc[j] = __builtin_amdgcn_mfma_f32_16x16x32_bf16(af, bfr, acc[j], 0, 0, 0);
            }
        }

        // epilogue: D row = quad*4 + r, col = nt*16 + ln
        float s0 = 0.f, s1 = 0.f, s2 = 0.f, s3 = 0.f;
#pragma unroll
        for (int nt = 0; nt < 8; ++nt) {
            float kb = kbv[nt], w2 = w2v[nt];
            s0 = fmaf(fmaxf(acc[nt][0] + bf2f(qv4[nt].x) + kb, 0.f), w2, s0);
            s1 = fmaf(fmaxf(acc[nt][1] + bf2f(qv4[nt].y) + kb, 0.f), w2, s1);
            s2 = fmaf(fmaxf(acc[nt][2] + bf2f(qv4[nt].z) + kb, 0.f), w2, s2);
            s3 = fmaf(fmaxf(acc[nt][3] + bf2f(qv4[nt].w) + kb, 0.f), w2, s3);
        }
        float sr[4] = {s0, s1, s2, s3};
#pragma unroll
        for (int r = 0; r < 4; ++r) {
            float s = sr[r];
            s += __shfl_xor(s, 1);
            s += __shfl_xor(s, 2);
            s += __shfl_xor(s, 4);
            s += __shfl_xor(s, 8);
            if (ln == 0) logits[rbase + quad * 4 + r] = s + b2f;
        }
    }
    __syncthreads();   // logits ready

    // ---- softmax over 256 logits: wave shfl reductions ----
    float lv = logits[t];
    float wm = lv;
#pragma unroll
    for (int d = 1; d < 64; d <<= 1) wm = fmaxf(wm, __shfl_xor(wm, d));
    if (lane == 0) red[wv] = wm;
    __syncthreads();
    float m = fmaxf(fmaxf(red[0], red[1]), fmaxf(red[2], red[3]));
    float e = __expf(lv - m);
    float es = e;
#pragma unroll
    for (int d = 1; d < 64; d <<= 1) es += __shfl_xor(es, d);
    if (lane == 0) red[4 + wv] = es;
    __syncthreads();
    float denom = red[4] + red[5] + red[6] + red[7];
    logits[t] = e / denom;
    __syncthreads();

    // ---- out[n,a,c] = x[n,a,c] + sum_b att[b] * v[n,b,c], float4 over c ----
    {
        int c4 = (t & 31) * 4, bg = t >> 5;          // 8 b-groups of 32
        const float* vp = v + (size_t)(n * PP + bg * 32) * CC + c4;
        float4 av = make_float4(0.f, 0.f, 0.f, 0.f);
#pragma unroll 4
        for (int b = 0; b < 32; ++b) {
            float w = logits[bg * 32 + b];
            float4 vv = *(const float4*)(vp + (size_t)b * CC);
            av.x = fmaf(w, vv.x, av.x); av.y = fmaf(w, vv.y, av.y);
            av.z = fmaf(w, vv.z, av.z); av.w = fmaf(w, vv.w, av.w);
        }
        *(float4*)&avp[bg * 128 + c4] = av;
    }
    __syncthreads();
    if (t < 128) {
        int oidx = (n * PP + a) * CC + t;
        float s = x[oidx];
#pragma unroll
        for (int g = 0; g < 8; ++g) s += avp[g * 128 + t];
        out[oidx] = s;
    }
}

extern "C" void kernel_launch(void* const* d_in, const int* in_sizes, int n_in,
                              void* d_out, int out_size, void* d_ws, size_t ws_size,
                              hipStream_t stream) {
    const float* x   = (const float*)d_in[0];
    const float* pos = (const float*)d_in[1];
    const float* Wq  = (const float*)d_in[2];
    const float* Wk  = (const float*)d_in[3];
    const float* Wv  = (const float*)d_in[4];
    const float* W1  = (const float*)d_in[5];
    const float* b1  = (const float*)d_in[6];
    const float* W2  = (const float*)d_in[7];
    const float* b2  = (const float*)d_in[8];
    const float* Wp1 = (const float*)d_in[9];
    const float* bp1 = (const float*)d_in[10];
    const float* Wp2 = (const float*)d_in[11];
    const float* bp2 = (const float*)d_in[12];
    float* out = (float*)d_out;

    float* ws   = (float*)d_ws;
    float* bvec = ws;                  // 128 f32
    float* kw   = bvec + 128;          // 262144 f32
    float* v    = kw + 262144;         // 262144 f32
    unsigned short* qwtb = (unsigned short*)(v + 262144);  // 262144 bf16
    unsigned short* W21f = qwtb + 262144;                  // 16384 bf16 (frag order)

    stage1_kernel<<<197, 256, 0, stream>>>(x, Wq, Wk, Wv, W1, b1, bp2, Wp2,
                                           qwtb, kw, v, W21f, bvec);
    attn_kernel<<<NB * PP, 256, 0, stream>>>(x, pos, Wp1, bp1, W2, b2,
                                             W21f, bvec, qwtb, kw, v, out);
}

// Round 14
// 140.679 us; speedup vs baseline: 1.1257x; 1.0106x over previous
//
#include <hip/hip_runtime.h>
#include <hip/hip_bf16.h>

#define NB 8
#define PP 256
#define CC 128
#define XS 132     // padded row stride for f32 LDS tiles

typedef __bf16 bf16x8 __attribute__((ext_vector_type(8)));
typedef float float4v __attribute__((ext_vector_type(4)));

__device__ __forceinline__ float bf2f(unsigned short u) {
    union { unsigned int i; float f; } x; x.i = ((unsigned int)u) << 16; return x.f;
}
__device__ __forceinline__ unsigned short f2bf(float f) {
    union { float f; unsigned int i; } x; x.f = f;
    unsigned int r = x.i + 0x7fffu + ((x.i >> 16) & 1u);  // RNE
    return (unsigned short)(r >> 16);
}
__device__ __forceinline__ unsigned int pkbf2(float a, float b) {
    union { __hip_bfloat162 b2; unsigned int u; } cv;
    cv.b2 = __float22bfloat162_rn(make_float2(a, b));   // v_cvt_pk_bf16_f32
    return cv.u;
}
__device__ __forceinline__ float lo2f(unsigned int u) {
    union { unsigned int i; float f; } x; x.i = u << 16; return x.f;
}
__device__ __forceinline__ float hi2f(unsigned int u) {
    union { unsigned int i; float f; } x; x.i = u & 0xffff0000u; return x.f;
}

// ONE prologue kernel, 197 blocks x 256 threads. W tiles staged in LDS as
// PACKED BF16 (32 KB, was 64 KB fp32): 2 blocks/CU and half the W LDS bytes
// (stage1 was LDS-issue-bound at 1 block/CU).
//  0..63   q: qwtb[n][j][b] = bf16( ((x@Wq)@W1)[b][j] )   (transposed)
//  64..127 k: kw = (x@Wk)@W1  (f32)
//  128..191 v: v = x@Wv       (f32)
//  192..195 W21f = (Wp2@W1) in bf16 MFMA-fragment order
//  196     bvec[j] = b1[j] + bp2@W1  (fp32 weights)
__global__ __launch_bounds__(256, 2) void stage1_kernel(
    const float* __restrict__ x, const float* __restrict__ Wq,
    const float* __restrict__ Wk, const float* __restrict__ Wv,
    const float* __restrict__ W1, const float* __restrict__ b1,
    const float* __restrict__ bp2, const float* __restrict__ Wp2,
    unsigned short* __restrict__ qwtb, float* __restrict__ kw,
    float* __restrict__ v, unsigned short* __restrict__ W21f,
    float* __restrict__ bvec)
{
    __shared__ __attribute__((aligned(16))) unsigned int WbufU[CC * CC / 2]; // bf16 pairs
    __shared__ __attribute__((aligned(16))) float xs[32 * XS];
    __shared__ __attribute__((aligned(16))) float tmp[32 * XS];
    const int t = threadIdx.x, bx = blockIdx.x;

    if (bx == 196) {
        if (t < 128) {
            float s = b1[t];
#pragma unroll 8
            for (int c = 0; c < CC; ++c) s = fmaf(bp2[c], W1[c * CC + t], s);
            bvec[t] = s;
        }
        return;
    }

    const int tc = t & 31, tr = t >> 5;
    const int j0 = tc * 4, r0 = tr * 4;
    const int jd = tc * 2;               // dword offset of j0 within a W row

    if (bx < 192) {
        const int kind = bx >> 6;            // 0=q, 1=k, 2=v
        const int row0 = (bx & 63) * 32;
        const float* Wsrc = (kind == 0) ? Wq : (kind == 1) ? Wk : Wv;
#pragma unroll 4
        for (int i = 0; i < 16; ++i) {
            float4 w = ((const float4*)Wsrc)[i * 256 + t];
            uint2 p; p.x = pkbf2(w.x, w.y); p.y = pkbf2(w.z, w.w);
            ((uint2*)WbufU)[i * 256 + t] = p;
        }
#pragma unroll
        for (int i = 0; i < 4; ++i) {
            int idx = i * 256 + t; int r = idx >> 5, c4 = idx & 31;
            *(float4*)&xs[r * XS + c4 * 4] =
                ((const float4*)(x + (size_t)(row0 + r) * CC))[c4];
        }
        __syncthreads();
        float4 acc[4];
#pragma unroll
        for (int i = 0; i < 4; ++i) acc[i] = make_float4(0.f, 0.f, 0.f, 0.f);
#pragma unroll 2
        for (int c4 = 0; c4 < 32; ++c4) {
            float4 xv0 = *(const float4*)&xs[(r0 + 0) * XS + c4 * 4];
            float4 xv1 = *(const float4*)&xs[(r0 + 1) * XS + c4 * 4];
            float4 xv2 = *(const float4*)&xs[(r0 + 2) * XS + c4 * 4];
            float4 xv3 = *(const float4*)&xs[(r0 + 3) * XS + c4 * 4];
            const float xr[4][4] = {{xv0.x, xv0.y, xv0.z, xv0.w},
                                    {xv1.x, xv1.y, xv1.z, xv1.w},
                                    {xv2.x, xv2.y, xv2.z, xv2.w},
                                    {xv3.x, xv3.y, xv3.z, xv3.w}};
#pragma unroll
            for (int cc = 0; cc < 4; ++cc) {
                uint2 wp = *(const uint2*)&WbufU[(c4 * 4 + cc) * 64 + jd];
                float w0 = lo2f(wp.x), w1 = hi2f(wp.x);
                float w2 = lo2f(wp.y), w3 = hi2f(wp.y);
#pragma unroll
                for (int i = 0; i < 4; ++i) {
                    acc[i].x = fmaf(xr[i][cc], w0, acc[i].x);
                    acc[i].y = fmaf(xr[i][cc], w1, acc[i].y);
                    acc[i].z = fmaf(xr[i][cc], w2, acc[i].z);
                    acc[i].w = fmaf(xr[i][cc], w3, acc[i].w);
                }
            }
        }
        if (kind == 2) {
#pragma unroll
            for (int i = 0; i < 4; ++i)
                *(float4*)&v[(size_t)(row0 + r0 + i) * CC + j0] = acc[i];
            return;
        }
        // write tmp, restage WbufU with W1 (bf16), second GEMM
#pragma unroll
        for (int i = 0; i < 4; ++i)
            *(float4*)&tmp[(r0 + i) * XS + j0] = acc[i];
        __syncthreads();
#pragma unroll 4
        for (int i = 0; i < 16; ++i) {
            float4 w = ((const float4*)W1)[i * 256 + t];
            uint2 p; p.x = pkbf2(w.x, w.y); p.y = pkbf2(w.z, w.w);
            ((uint2*)WbufU)[i * 256 + t] = p;
        }
        __syncthreads();
        float4 acc2[4];
#pragma unroll
        for (int i = 0; i < 4; ++i) acc2[i] = make_float4(0.f, 0.f, 0.f, 0.f);
#pragma unroll 2
        for (int c4 = 0; c4 < 32; ++c4) {
            float4 xv0 = *(const float4*)&tmp[(r0 + 0) * XS + c4 * 4];
            float4 xv1 = *(const float4*)&tmp[(r0 + 1) * XS + c4 * 4];
            float4 xv2 = *(const float4*)&tmp[(r0 + 2) * XS + c4 * 4];
            float4 xv3 = *(const float4*)&tmp[(r0 + 3) * XS + c4 * 4];
            const float xr[4][4] = {{xv0.x, xv0.y, xv0.z, xv0.w},
                                    {xv1.x, xv1.y, xv1.z, xv1.w},
                                    {xv2.x, xv2.y, xv2.z, xv2.w},
                                    {xv3.x, xv3.y, xv3.z, xv3.w}};
#pragma unroll
            for (int cc = 0; cc < 4; ++cc) {
                uint2 wp = *(const uint2*)&WbufU[(c4 * 4 + cc) * 64 + jd];
                float w0 = lo2f(wp.x), w1 = hi2f(wp.x);
                float w2 = lo2f(wp.y), w3 = hi2f(wp.y);
#pragma unroll
                for (int i = 0; i < 4; ++i) {
                    acc2[i].x = fmaf(xr[i][cc], w0, acc2[i].x);
                    acc2[i].y = fmaf(xr[i][cc], w1, acc2[i].y);
                    acc2[i].z = fmaf(xr[i][cc], w2, acc2[i].z);
                    acc2[i].w = fmaf(xr[i][cc], w3, acc2[i].w);
                }
            }
        }
        if (kind == 0) {
            int n = row0 >> 8, b0 = row0 & 255;
            const float a2[4][4] = {{acc2[0].x, acc2[0].y, acc2[0].z, acc2[0].w},
                                    {acc2[1].x, acc2[1].y, acc2[1].z, acc2[1].w},
                                    {acc2[2].x, acc2[2].y, acc2[2].z, acc2[2].w},
                                    {acc2[3].x, acc2[3].y, acc2[3].z, acc2[3].w}};
#pragma unroll
            for (int jj = 0; jj < 4; ++jj) {
                ushort4 pk;
                pk.x = f2bf(a2[0][jj]); pk.y = f2bf(a2[1][jj]);
                pk.z = f2bf(a2[2][jj]); pk.w = f2bf(a2[3][jj]);
                *(ushort4*)(qwtb + (size_t)(n * CC + j0 + jj) * PP + b0 + r0) = pk;
            }
        } else {
#pragma unroll
            for (int i = 0; i < 4; ++i)
                *(float4*)&kw[(size_t)(row0 + r0 + i) * CC + j0] = acc2[i];
        }
    } else {
        // W21f: rows of Wp2 @ W1 (bf16 W tile), stored bf16 fragment order
        const int row0 = (bx - 192) * 32;
#pragma unroll 4
        for (int i = 0; i < 16; ++i) {
            float4 w = ((const float4*)W1)[i * 256 + t];
            uint2 p; p.x = pkbf2(w.x, w.y); p.y = pkbf2(w.z, w.w);
            ((uint2*)WbufU)[i * 256 + t] = p;
        }
#pragma unroll
        for (int i = 0; i < 4; ++i) {
            int idx = i * 256 + t; int r = idx >> 5, c4 = idx & 31;
            *(float4*)&xs[r * XS + c4 * 4] =
                ((const float4*)(Wp2 + (size_t)(row0 + r) * CC))[c4];
        }
        __syncthreads();
        float4 acc[4];
#pragma unroll
        for (int i = 0; i < 4; ++i) acc[i] = make_float4(0.f, 0.f, 0.f, 0.f);
#pragma unroll 2
        for (int c4 = 0; c4 < 32; ++c4) {
            float4 xv0 = *(const float4*)&xs[(r0 + 0) * XS + c4 * 4];
            float4 xv1 = *(const float4*)&xs[(r0 + 1) * XS + c4 * 4];
            float4 xv2 = *(const float4*)&xs[(r0 + 2) * XS + c4 * 4];
            float4 xv3 = *(const float4*)&xs[(r0 + 3) * XS + c4 * 4];
            const float xr[4][4] = {{xv0.x, xv0.y, xv0.z, xv0.w},
                                    {xv1.x, xv1.y, xv1.z, xv1.w},
                                    {xv2.x, xv2.y, xv2.z, xv2.w},
                                    {xv3.x, xv3.y, xv3.z, xv3.w}};
#pragma unroll
            for (int cc = 0; cc < 4; ++cc) {
                uint2 wp = *(const uint2*)&WbufU[(c4 * 4 + cc) * 64 + jd];
                float w0 = lo2f(wp.x), w1 = hi2f(wp.x);
                float w2 = lo2f(wp.y), w3 = hi2f(wp.y);
#pragma unroll
                for (int i = 0; i < 4; ++i) {
                    acc[i].x = fmaf(xr[i][cc], w0, acc[i].x);
                    acc[i].y = fmaf(xr[i][cc], w1, acc[i].y);
                    acc[i].z = fmaf(xr[i][cc], w2, acc[i].z);
                    acc[i].w = fmaf(xr[i][cc], w3, acc[i].w);
                }
            }
        }
        const float a4[4][4] = {{acc[0].x, acc[0].y, acc[0].z, acc[0].w},
                                {acc[1].x, acc[1].y, acc[1].z, acc[1].w},
                                {acc[2].x, acc[2].y, acc[2].z, acc[2].w},
                                {acc[3].x, acc[3].y, acc[3].z, acc[3].w}};
#pragma unroll
        for (int i = 0; i < 4; ++i)
#pragma unroll
            for (int jj = 0; jj < 4; ++jj) {
                int k = row0 + r0 + i, j = j0 + jj;
                int kk = k >> 5, qd = (k >> 3) & 3, e = k & 7;
                int jt = j >> 4, ln = j & 15, lane = qd * 16 + ln;
                W21f[(((kk * 8 + jt) * 64) + lane) * 8 + e] = f2bf(a4[i][jj]);
            }
    }
}

// One block per (n,a). R13 loop body VERBATIM (frozen). Changes: LDS alias
// pool (GEMM-phase constants union'd with avp) -> 37.9 KB -> 4 blocks/CU;
// HW packed bf16 cvt in the A-build.
__global__ __launch_bounds__(256, 4) void attn_kernel(
    const float* __restrict__ x, const float* __restrict__ pos,
    const float* __restrict__ Wp1, const float* __restrict__ bp1,
    const float* __restrict__ W2, const float* __restrict__ b2,
    const unsigned short* __restrict__ W21f, const float* __restrict__ bvec,
    const unsigned short* __restrict__ qwtb, const float* __restrict__ kw,
    const float* __restrict__ v, float* __restrict__ out)
{
    __shared__ __attribute__((aligned(16))) unsigned short Bs[128 * 128]; // frag order
    __shared__ __attribute__((aligned(16))) float pool[1024];  // GEMM consts / avp
    __shared__ float logits[PP];
    __shared__ float red[8];

    float* const wa   = pool;          // [128]  dead after logits barrier
    float* const wb   = pool + 128;    // [128]
    float* const bpv  = pool + 256;    // [128]
    float* const p0s  = pool + 384;    // [256]
    float* const p1s  = pool + 640;    // [256]
    float* const avp  = pool;          // [1024] live only after logits barrier

    const int t = threadIdx.x;
    const int n = blockIdx.x >> 8, a = blockIdx.x & 255;
    const int lane = t & 63, wv = t >> 6;
    const int ln = lane & 15, quad = lane >> 4;

    if (t < CC) {
        wa[t]  = Wp1[t];
        wb[t]  = Wp1[CC + t];
        bpv[t] = bp1[t];
    }
    {
        const float2* pr = (const float2*)(pos + (size_t)(n * PP + a) * PP * 2);
        float2 pp = pr[t];
        p0s[t] = pp.x;
        p1s[t] = pp.y;
    }
    {   // stage Bs: straight 16B copies (global coalesced, LDS conflict-free)
        const uint4* src = (const uint4*)W21f;
        uint4* dst = (uint4*)Bs;
#pragma unroll
        for (int i = 0; i < 8; ++i) dst[i * 256 + t] = src[i * 256 + t];
    }
    const float b2f = b2[0];

    // per-lane epilogue constants (col j = nt*16 + ln)
    float w2v[8], kbv[8];
    {
        const float* kwrow = kw + (size_t)(n * PP + a) * CC;
#pragma unroll
        for (int nt = 0; nt < 8; ++nt) {
            int j = nt * 16 + ln;
            w2v[nt] = W2[j];
            kbv[nt] = bvec[j] - kwrow[j];
        }
    }
    __syncthreads();

#pragma unroll 1
    for (int chunk = 0; chunk < 4; ++chunk) {
        const int rbase = chunk * 64 + wv * 16;
        const float P0 = p0s[rbase + ln];
        const float P1 = p1s[rbase + ln];

        // prefetch qw epilogue values (bf16 transposed [n][j][b]) — drains behind MFMA
        ushort4 qv4[8];
#pragma unroll
        for (int nt = 0; nt < 8; ++nt)
            qv4[nt] = *(const ushort4*)(qwtb + (size_t)(n * CC + nt * 16 + ln) * PP
                                        + rbase + quad * 4);

        float4v acc[8];
#pragma unroll
        for (int j = 0; j < 8; ++j) acc[j] = (float4v)0.f;

#pragma unroll 1
        for (int kk = 0; kk < 4; ++kk) {
            const int ko = kk * 32 + quad * 8;
            // A-fragment in registers from LDS broadcast reads: A[m=ln][k=ko+e]
            float4 a0 = *(const float4*)&wa[ko],  a1 = *(const float4*)&wa[ko + 4];
            float4 c0 = *(const float4*)&wb[ko],  c1 = *(const float4*)&wb[ko + 4];
            float4 d0 = *(const float4*)&bpv[ko], d1 = *(const float4*)&bpv[ko + 4];
            float h0 = fmaxf(fmaf(P0, a0.x, fmaf(P1, c0.x, d0.x)), 0.f);
            float h1 = fmaxf(fmaf(P0, a0.y, fmaf(P1, c0.y, d0.y)), 0.f);
            float h2 = fmaxf(fmaf(P0, a0.z, fmaf(P1, c0.z, d0.z)), 0.f);
            float h3 = fmaxf(fmaf(P0, a0.w, fmaf(P1, c0.w, d0.w)), 0.f);
            float h4 = fmaxf(fmaf(P0, a1.x, fmaf(P1, c1.x, d1.x)), 0.f);
            float h5 = fmaxf(fmaf(P0, a1.y, fmaf(P1, c1.y, d1.y)), 0.f);
            float h6 = fmaxf(fmaf(P0, a1.z, fmaf(P1, c1.z, d1.z)), 0.f);
            float h7 = fmaxf(fmaf(P0, a1.w, fmaf(P1, c1.w, d1.w)), 0.f);
            union { bf16x8 v8; unsigned int u[4]; } cv;
            cv.u[0] = pkbf2(h0, h1); cv.u[1] = pkbf2(h2, h3);
            cv.u[2] = pkbf2(h4, h5); cv.u[3] = pkbf2(h6, h7);
            bf16x8 af = cv.v8;
#pragma unroll
            for (int j = 0; j < 8; ++j) {
                bf16x8 bfr = *(const bf16x8*)(Bs + (((kk * 8 + j) * 64) + lane) * 8);
                acc[j] = __builtin_amdgcn_mfma_f32_16x16x32_bf16(af, bfr, acc[j], 0, 0, 0);
            }
        }

        // epilogue: D row = quad*4 + r, col = nt*16 + ln
        float s0 = 0.f, s1 = 0.f, s2 = 0.f, s3 = 0.f;
#pragma unroll
        for (int nt = 0; nt < 8; ++nt) {
            float kb = kbv[nt], w2 = w2v[nt];
            s0 = fmaf(fmaxf(acc[nt][0] + bf2f(qv4[nt].x) + kb, 0.f), w2, s0);
            s1 = fmaf(fmaxf(acc[nt][1] + bf2f(qv4[nt].y) + kb, 0.f), w2, s1);
            s2 = fmaf(fmaxf(acc[nt][2] + bf2f(qv4[nt].z) + kb, 0.f), w2, s2);
            s3 = fmaf(fmaxf(acc[nt][3] + bf2f(qv4[nt].w) + kb, 0.f), w2, s3);
        }
        float sr[4] = {s0, s1, s2, s3};
#pragma unroll
        for (int r = 0; r < 4; ++r) {
            float s = sr[r];
            s += __shfl_xor(s, 1);
            s += __shfl_xor(s, 2);
            s += __shfl_xor(s, 4);
            s += __shfl_xor(s, 8);
            if (ln == 0) logits[rbase + quad * 4 + r] = s + b2f;
        }
    }
    __syncthreads();   // logits ready; pool's GEMM-phase contents now dead

    // ---- softmax over 256 logits: wave shfl reductions ----
    float lv = logits[t];
    float wm = lv;
#pragma unroll
    for (int d = 1; d < 64; d <<= 1) wm = fmaxf(wm, __shfl_xor(wm, d));
    if (lane == 0) red[wv] = wm;
    __syncthreads();
    float m = fmaxf(fmaxf(red[0], red[1]), fmaxf(red[2], red[3]));
    float e = __expf(lv - m);
    float es = e;
#pragma unroll
    for (int d = 1; d < 64; d <<= 1) es += __shfl_xor(es, d);
    if (lane == 0) red[4 + wv] = es;
    __syncthreads();
    float denom = red[4] + red[5] + red[6] + red[7];
    logits[t] = e / denom;
    __syncthreads();

    // ---- out[n,a,c] = x[n,a,c] + sum_b att[b] * v[n,b,c], float4 over c ----
    {
        int c4 = (t & 31) * 4, bg = t >> 5;          // 8 b-groups of 32
        const float* vp = v + (size_t)(n * PP + bg * 32) * CC + c4;
        float4 av = make_float4(0.f, 0.f, 0.f, 0.f);
#pragma unroll 4
        for (int b = 0; b < 32; ++b) {
            float w = logits[bg * 32 + b];
            float4 vv = *(const float4*)(vp + (size_t)b * CC);
            av.x = fmaf(w, vv.x, av.x); av.y = fmaf(w, vv.y, av.y);
            av.z = fmaf(w, vv.z, av.z); av.w = fmaf(w, vv.w, av.w);
        }
        *(float4*)&avp[bg * 128 + c4] = av;
    }
    __syncthreads();
    if (t < 128) {
        int oidx = (n * PP + a) * CC + t;
        float s = x[oidx];
#pragma unroll
        for (int g = 0; g < 8; ++g) s += avp[g * 128 + t];
        out[oidx] = s;
    }
}

extern "C" void kernel_launch(void* const* d_in, const int* in_sizes, int n_in,
                              void* d_out, int out_size, void* d_ws, size_t ws_size,
                              hipStream_t stream) {
    const float* x   = (const float*)d_in[0];
    const float* pos = (const float*)d_in[1];
    const float* Wq  = (const float*)d_in[2];
    const float* Wk  = (const float*)d_in[3];
    const float* Wv  = (const float*)d_in[4];
    const float* W1  = (const float*)d_in[5];
    const float* b1  = (const float*)d_in[6];
    const float* W2  = (const float*)d_in[7];
    const float* b2  = (const float*)d_in[8];
    const float* Wp1 = (const float*)d_in[9];
    const float* bp1 = (const float*)d_in[10];
    const float* Wp2 = (const float*)d_in[11];
    const float* bp2 = (const float*)d_in[12];
    float* out = (float*)d_out;

    float* ws   = (float*)d_ws;
    float* bvec = ws;                  // 128 f32
    float* kw   = bvec + 128;          // 262144 f32
    float* v    = kw + 262144;         // 262144 f32
    unsigned short* qwtb = (unsigned short*)(v + 262144);  // 262144 bf16
    unsigned short* W21f = qwtb + 262144;                  // 16384 bf16 (frag order)

    stage1_kernel<<<197, 256, 0, stream>>>(x, Wq, Wk, Wv, W1, b1, bp2, Wp2,
                                           qwtb, kw, v, W21f, bvec);
    attn_kernel<<<NB * PP, 256, 0, stream>>>(x, pos, Wp1, bp1, W2, b2,
                                             W21f, bvec, qwtb, kw, v, out);
}